// Round 2
// baseline (909.071 us; speedup 1.0000x reference)
//
#include <hip/hip_runtime.h>
#include <math.h>

#define LEAKY1(v) ((v) >= 0.f ? (v) : 0.01f*(v))
#define LEAKY2(v) ((v) >= 0.f ? (v) : 0.2f*(v))

// ---------------------------------------------------------------------------
// Kernel 1: conv1 (103ch 15x15 -> 32ch 13x13) + bias + leaky(0.01) + BN(eval)
// One block per batch image. Input staged to LDS in 2 channel chunks.
// Thread (oy = tid&15 [13 active], g = tid>>4): 2 output channels, 1 row.
// ---------------------------------------------------------------------------
__global__ __launch_bounds__(256) void conv1_kernel(
    const float* __restrict__ x, const float* __restrict__ w,
    const float* __restrict__ cb, const float* __restrict__ bng,
    const float* __restrict__ bnb, const float* __restrict__ bnm,
    const float* __restrict__ bnv, float* __restrict__ x1out) {
  __shared__ float s_in[52][15][16];   // 49,920 B
  const int b   = blockIdx.x;
  const int tid = threadIdx.x;
  const float* xin = x + (size_t)b * (103 * 225);
  const int oy = tid & 15;
  const int g  = tid >> 4;
  const int oc0 = g * 2, oc1 = oc0 + 1;

  float acc0[13], acc1[13];
#pragma unroll
  for (int j = 0; j < 13; ++j) { acc0[j] = 0.f; acc1[j] = 0.f; }

  for (int c0 = 0; c0 < 103; c0 += 52) {
    const int cn = (103 - c0) < 52 ? (103 - c0) : 52;
    __syncthreads();   // protect previous chunk's LDS reads
    for (int i = tid; i < cn * 225; i += 256) {
      int ic = i / 225;
      int r  = i - ic * 225;
      int yy = r / 15;
      int xx = r - yy * 15;
      s_in[ic][yy][xx] = xin[(size_t)(c0 + ic) * 225 + r];
    }
    __syncthreads();
    if (oy < 13) {
      for (int ic = 0; ic < cn; ++ic) {
        const float* wp0 = w + ((size_t)oc0 * 103 + (c0 + ic)) * 9;
        const float* wp1 = w + ((size_t)oc1 * 103 + (c0 + ic)) * 9;
        float w0[9], w1[9];
#pragma unroll
        for (int k = 0; k < 9; ++k) { w0[k] = wp0[k]; w1[k] = wp1[k]; }
#pragma unroll
        for (int ky = 0; ky < 3; ++ky) {
          float rin[15];
#pragma unroll
          for (int j = 0; j < 15; ++j) rin[j] = s_in[ic][oy + ky][j];
#pragma unroll
          for (int ox = 0; ox < 13; ++ox) {
            acc0[ox] = fmaf(w0[ky*3+2], rin[ox+2],
                       fmaf(w0[ky*3+1], rin[ox+1],
                       fmaf(w0[ky*3+0], rin[ox+0], acc0[ox])));
            acc1[ox] = fmaf(w1[ky*3+2], rin[ox+2],
                       fmaf(w1[ky*3+1], rin[ox+1],
                       fmaf(w1[ky*3+0], rin[ox+0], acc1[ox])));
          }
        }
      }
    }
  }

  if (oy < 13) {
    const float bias0 = cb[oc0], bias1 = cb[oc1];
    const float sc0 = bng[oc0] * rsqrtf(bnv[oc0] + 1e-5f);
    const float sc1 = bng[oc1] * rsqrtf(bnv[oc1] + 1e-5f);
    const float sh0 = bnb[oc0] - bnm[oc0] * sc0;
    const float sh1 = bnb[oc1] - bnm[oc1] * sc1;
    float* o0 = x1out + ((size_t)b * 32 + oc0) * 169 + oy * 13;
    float* o1 = x1out + ((size_t)b * 32 + oc1) * 169 + oy * 13;
#pragma unroll
    for (int ox = 0; ox < 13; ++ox) {
      float v0 = LEAKY1(acc0[ox] + bias0);
      float v1 = LEAKY1(acc1[ox] + bias1);
      o0[ox] = v0 * sc0 + sh0;
      o1[ox] = v1 * sc1 + sh1;
    }
  }
}

// ---------------------------------------------------------------------------
// Kernel 2: conv2 (32ch 13x13 -> 64ch 11x11) + bias + leaky(0.01) + BN(eval)
// One block per batch. Thread: 4 output channels, 1 row (oy = tid&15, 11 active).
// Writes x2 (output 1 of the reference) into d_out at offset 1024*256.
// ---------------------------------------------------------------------------
__global__ __launch_bounds__(256) void conv2_kernel(
    const float* __restrict__ x1, const float* __restrict__ w,
    const float* __restrict__ cb, const float* __restrict__ bng,
    const float* __restrict__ bnb, const float* __restrict__ bnm,
    const float* __restrict__ bnv, float* __restrict__ x2out) {
  __shared__ float s_in[32][13][16];   // 26,624 B
  const int b   = blockIdx.x;
  const int tid = threadIdx.x;
  const float* xin = x1 + (size_t)b * (32 * 169);
  for (int i = tid; i < 32 * 169; i += 256) {
    int ic = i / 169;
    int r  = i - ic * 169;
    int yy = r / 13;
    int xx = r - yy * 13;
    s_in[ic][yy][xx] = xin[i];
  }
  __syncthreads();
  const int oy = tid & 15;
  const int g  = tid >> 4;
  if (oy >= 11) return;

  float acc[4][11];
#pragma unroll
  for (int o = 0; o < 4; ++o)
#pragma unroll
    for (int j = 0; j < 11; ++j) acc[o][j] = 0.f;

  const int ocb = g * 4;
  for (int ic = 0; ic < 32; ++ic) {
    float wr[4][9];
#pragma unroll
    for (int o = 0; o < 4; ++o)
#pragma unroll
      for (int k = 0; k < 9; ++k)
        wr[o][k] = w[((size_t)(ocb + o) * 32 + ic) * 9 + k];
#pragma unroll
    for (int ky = 0; ky < 3; ++ky) {
      float rin[13];
#pragma unroll
      for (int j = 0; j < 13; ++j) rin[j] = s_in[ic][oy + ky][j];
#pragma unroll
      for (int ox = 0; ox < 11; ++ox) {
#pragma unroll
        for (int o = 0; o < 4; ++o) {
          acc[o][ox] = fmaf(wr[o][ky*3+2], rin[ox+2],
                       fmaf(wr[o][ky*3+1], rin[ox+1],
                       fmaf(wr[o][ky*3+0], rin[ox+0], acc[o][ox])));
        }
      }
    }
  }

#pragma unroll
  for (int o = 0; o < 4; ++o) {
    const int oc = ocb + o;
    const float bias = cb[oc];
    const float sc = bng[oc] * rsqrtf(bnv[oc] + 1e-5f);
    const float sh = bnb[oc] - bnm[oc] * sc;
    float* op = x2out + ((size_t)b * 64 + oc) * 121 + oy * 11;
#pragma unroll
    for (int ox = 0; ox < 11; ++ox) {
      float v = LEAKY1(acc[o][ox] + bias);
      op[ox] = v * sc + sh;
    }
  }
}

// ---------------------------------------------------------------------------
// Kernel 3: SAM + SGraph + DGraph per batch element. One block per batch.
// ---------------------------------------------------------------------------
__global__ __launch_bounds__(256) void sam_graph_kernel(
    const float* __restrict__ x2,       // [B,64,121]
    const float* __restrict__ fc_sam_w, // [4,64]
    const float* __restrict__ conv_t_w, // [64,64]
    const float* __restrict__ conv_t_b, // [64]
    const float* __restrict__ s_adj_w,  // [4,4]
    const float* __restrict__ s_w_w,    // [64,64]
    const float* __restrict__ s_w_b,    // [64]
    const float* __restrict__ d_co_w,   // [4,128]
    const float* __restrict__ d_co_b,   // [4]
    const float* __restrict__ d_gamma,  // [1]
    const float* __restrict__ d_dw_w,   // [64,64]
    const float* __restrict__ d_dw_b,   // [64]
    float* __restrict__ x6) {           // [B,256]
  __shared__ float s_flat[64][124];
  __shared__ float s_xt[64][124];
  __shared__ float s_mask[4][124];
  __shared__ float s_x3[64][4];
  __shared__ float s_a[64][4];
  __shared__ float s_x4[64][4];
  __shared__ float s_att[64][66];       // energy, then att
  __shared__ float s_xg[64][4];
  __shared__ float s_dadj[4][4];
  __shared__ float s_y[64][4];

  const int b   = blockIdx.x;
  const int tid = threadIdx.x;
  const float* f = x2 + (size_t)b * 7744;

  // stage flat [64][121]
  for (int i = tid; i < 7744; i += 256) {
    int c = i / 121, l = i - c * 121;
    s_flat[c][l] = f[i];
  }
  __syncthreads();

  // mask[n][l] = sigmoid(sum_c fc_sam_w[n][c] * flat[c][l])
  for (int i = tid; i < 4 * 121; i += 256) {
    int n = i / 121, l = i - n * 121;
    float s = 0.f;
    for (int c = 0; c < 64; ++c) s = fmaf(fc_sam_w[n*64 + c], s_flat[c][l], s);
    s_mask[n][l] = 1.f / (1.f + __expf(-s));
  }
  // xt[o][l] = sum_c conv_t_w[o][c] * flat[c][l] + conv_t_b[o]
  for (int i = tid; i < 64 * 121; i += 256) {
    int c = i / 121, l = i - c * 121;
    float s = conv_t_b[c];
    for (int k = 0; k < 64; ++k) s = fmaf(conv_t_w[c*64 + k], s_flat[k][l], s);
    s_xt[c][l] = s;
  }
  __syncthreads();

  // x3[c][n] = sum_l xt[c][l]*mask[n][l]   (exactly 256 outputs)
  {
    int c = tid >> 2, n = tid & 3;
    float s = 0.f;
    for (int l = 0; l < 121; ++l) s = fmaf(s_xt[c][l], s_mask[n][l], s);
    s_x3[c][n] = s;
  }
  __syncthreads();

  // a[f][m] = leaky(sum_n s_adj_w[m][n]*x3[f][n], 0.2)
  {
    int fi = tid >> 2, m = tid & 3;
    float s = 0.f;
#pragma unroll
    for (int n = 0; n < 4; ++n) s = fmaf(s_adj_w[m*4 + n], s_x3[fi][n], s);
    s_a[fi][m] = LEAKY2(s);
  }
  __syncthreads();

  // sg[o][n] = leaky(sum_f s_w_w[o][f]*a[f][n] + s_w_b[o], 0.2); x4 = sg + x3
  {
    int o = tid >> 2, n = tid & 3;
    float s = s_w_b[o];
    for (int ff = 0; ff < 64; ++ff) s = fmaf(s_w_w[o*64 + ff], s_a[ff][n], s);
    s = LEAKY2(s);
    s_x4[o][n] = s + s_x3[o][n];
  }
  __syncthreads();

  // energy[c][d] = sum_n x4[c][n]*x4[d][n]
  for (int i = tid; i < 4096; i += 256) {
    int c = i >> 6, d = i & 63;
    float s = 0.f;
#pragma unroll
    for (int n = 0; n < 4; ++n) s = fmaf(s_x4[c][n], s_x4[d][n], s);
    s_att[c][d] = s;
  }
  __syncthreads();

  // softmax over d of (rowmax - energy)  == softmax of (-energy) == exp(rowmin - energy)/sum
  if (tid < 64) {
    int c = tid;
    float mn = 1e30f;
    for (int d = 0; d < 64; ++d) mn = fminf(mn, s_att[c][d]);
    float ssum = 0.f;
    for (int d = 0; d < 64; ++d) {
      float e = __expf(mn - s_att[c][d]);
      s_att[c][d] = e;
      ssum += e;
    }
    float inv = 1.f / ssum;
    for (int d = 0; d < 64; ++d) s_att[c][d] *= inv;
  }
  __syncthreads();

  // out[c][n] = sum_d att[c][d]*x4[d][n]; x_glb = gamma*out + x4
  const float gamma = d_gamma[0];
  {
    int c = tid >> 2, n = tid & 3;
    float s = 0.f;
    for (int d = 0; d < 64; ++d) s = fmaf(s_att[c][d], s_x4[d][n], s);
    s_xg[c][n] = gamma * s + s_x4[c][n];
  }
  __syncthreads();

  // dadj[m][n] = sigmoid(sum_k d_co_w[m][k]*cat[k][n] + d_co_b[m]), cat=[xg;x4]
  if (tid < 16) {
    int m = tid >> 2, n = tid & 3;
    float s = d_co_b[m];
    for (int k = 0; k < 64; ++k) s = fmaf(d_co_w[m*128 + k],      s_xg[k][n], s);
    for (int k = 0; k < 64; ++k) s = fmaf(d_co_w[m*128 + 64 + k], s_x4[k][n], s);
    s_dadj[m][n] = 1.f / (1.f + __expf(-s));
  }
  __syncthreads();

  // y[c][m] = leaky(sum_n x4[c][n]*dadj[n][m], 0.2)
  {
    int c = tid >> 2, m = tid & 3;
    float s = 0.f;
#pragma unroll
    for (int n = 0; n < 4; ++n) s = fmaf(s_x4[c][n], s_dadj[n][m], s);
    s_y[c][m] = LEAKY2(s);
  }
  __syncthreads();

  // y2[o][n] = leaky(sum_f d_dw_w[o][f]*y[f][n] + d_dw_b[o], 0.2); x5 = y2 + x4
  {
    int o = tid >> 2, n = tid & 3;
    float s = d_dw_b[o];
    for (int ff = 0; ff < 64; ++ff) s = fmaf(d_dw_w[o*64 + ff], s_y[ff][n], s);
    s = LEAKY2(s);
    x6[(size_t)b * 256 + tid] = s + s_x4[o][n];
  }
}

// ---------------------------------------------------------------------------
extern "C" void kernel_launch(void* const* d_in, const int* in_sizes, int n_in,
                              void* d_out, int out_size, void* d_ws, size_t ws_size,
                              hipStream_t stream) {
  const float* x     = (const float*)d_in[0];
  const float* c1w   = (const float*)d_in[1];
  const float* c1b   = (const float*)d_in[2];
  const float* bn1g  = (const float*)d_in[3];
  const float* bn1b  = (const float*)d_in[4];
  const float* bn1m  = (const float*)d_in[5];
  const float* bn1v  = (const float*)d_in[6];
  const float* c2w   = (const float*)d_in[7];
  const float* c2b   = (const float*)d_in[8];
  const float* bn2g  = (const float*)d_in[9];
  const float* bn2b  = (const float*)d_in[10];
  const float* bn2m  = (const float*)d_in[11];
  const float* bn2v  = (const float*)d_in[12];
  const float* fcw   = (const float*)d_in[13];
  const float* ctw   = (const float*)d_in[14];
  const float* ctb   = (const float*)d_in[15];
  const float* sadj  = (const float*)d_in[16];
  const float* sww   = (const float*)d_in[17];
  const float* swb   = (const float*)d_in[18];
  const float* dcow  = (const float*)d_in[19];
  const float* dcob  = (const float*)d_in[20];
  const float* dgam  = (const float*)d_in[21];
  const float* ddww  = (const float*)d_in[22];
  const float* ddwb  = (const float*)d_in[23];

  float* out = (float*)d_out;
  float* x6  = out;                      // [1024,256]
  float* x2  = out + (size_t)1024 * 256; // [1024,64,121]
  float* x1  = (float*)d_ws;             // [1024,32,169]  (22.2 MB scratch)

  conv1_kernel<<<1024, 256, 0, stream>>>(x, c1w, c1b, bn1g, bn1b, bn1m, bn1v, x1);
  conv2_kernel<<<1024, 256, 0, stream>>>(x1, c2w, c2b, bn2g, bn2b, bn2m, bn2v, x2);
  sam_graph_kernel<<<1024, 256, 0, stream>>>(x2, fcw, ctw, ctb, sadj, sww, swb,
                                             dcow, dcob, dgam, ddww, ddwb, x6);
}

// Round 3
// 625.290 us; speedup vs baseline: 1.4538x; 1.4538x over previous
//
#include <hip/hip_runtime.h>
#include <math.h>

#define LEAKY1(v) ((v) >= 0.f ? (v) : 0.01f*(v))
#define LEAKY2(v) ((v) >= 0.f ? (v) : 0.2f*(v))

// ---------------------------------------------------------------------------
// Kernel 1: conv1 (103ch 15x15 -> 32ch 13x13) + bias + leaky(0.01) + BN(eval)
// One block per batch image. Input staged in LDS (2 channel chunks), row
// stride padded to 17 floats (17 invertible mod 32 -> conflict-free reads).
// Thread = (oy = tid&15 [13 active], h = (tid>>4)&1 half-row, g = tid>>5):
// 4 output channels x 7 (or 6) output columns. ~27 LDS reads vs ~252 FMA
// per input channel -> VALU-bound, not LDS-bound.
// ---------------------------------------------------------------------------
__global__ __launch_bounds__(256) void conv1_kernel(
    const float* __restrict__ x, const float* __restrict__ w,
    const float* __restrict__ cb, const float* __restrict__ bng,
    const float* __restrict__ bnb, const float* __restrict__ bnm,
    const float* __restrict__ bnv, float* __restrict__ x1out) {
  __shared__ float s_in[52][15][17];   // 53,040 B
  const int b   = blockIdx.x;
  const int tid = threadIdx.x;
  const float* xin = x + (size_t)b * (103 * 225);
  const int oy  = tid & 15;
  const int h   = (tid >> 4) & 1;
  const int g   = tid >> 5;           // 0..7
  const int oc0 = g * 4;
  const int ox0 = h * 7;              // h=0: ox 0..6 (7), h=1: ox 7..12 (6)

  float acc[4][7];
#pragma unroll
  for (int o = 0; o < 4; ++o)
#pragma unroll
    for (int j = 0; j < 7; ++j) acc[o][j] = 0.f;

  for (int c0 = 0; c0 < 103; c0 += 52) {
    const int cn = (103 - c0) < 52 ? (103 - c0) : 52;
    __syncthreads();   // protect previous chunk's LDS reads
    for (int i = tid; i < cn * 225; i += 256) {
      int ic = i / 225;
      int r  = i - ic * 225;
      int yy = r / 15;
      int xx = r - yy * 15;
      s_in[ic][yy][xx] = xin[(size_t)(c0 + ic) * 225 + r];
    }
    __syncthreads();
    if (oy < 13) {
      for (int ic = 0; ic < cn; ++ic) {
        const float* wp = w + ((size_t)oc0 * 103 + (c0 + ic)) * 9;
        float wr[4][9];
#pragma unroll
        for (int o = 0; o < 4; ++o)
#pragma unroll
          for (int k = 0; k < 9; ++k) wr[o][k] = wp[(size_t)o * 927 + k];
#pragma unroll
        for (int ky = 0; ky < 3; ++ky) {
          float rin[9];
#pragma unroll
          for (int j = 0; j < 9; ++j) rin[j] = s_in[ic][oy + ky][ox0 + j];
#pragma unroll
          for (int ox = 0; ox < 7; ++ox) {
#pragma unroll
            for (int o = 0; o < 4; ++o) {
              acc[o][ox] = fmaf(wr[o][ky*3+2], rin[ox+2],
                           fmaf(wr[o][ky*3+1], rin[ox+1],
                           fmaf(wr[o][ky*3+0], rin[ox+0], acc[o][ox])));
            }
          }
        }
      }
    }
  }

  if (oy < 13) {
    const int nout = 7 - h;   // h=1's 7th output is garbage (reads pad) - not stored
#pragma unroll
    for (int o = 0; o < 4; ++o) {
      const int oc = oc0 + o;
      const float bias = cb[oc];
      const float sc = bng[oc] * rsqrtf(bnv[oc] + 1e-5f);
      const float sh = bnb[oc] - bnm[oc] * sc;
      float* op = x1out + ((size_t)b * 32 + oc) * 169 + oy * 13 + ox0;
      for (int ox = 0; ox < nout; ++ox) {
        float v = LEAKY1(acc[o][ox] + bias);
        op[ox] = v * sc + sh;
      }
    }
  }
}

// ---------------------------------------------------------------------------
// Kernel 2: conv2 (32ch 13x13 -> 64ch 11x11) + bias + leaky(0.01) + BN(eval)
// One block per batch. Thread: 4 output channels, 1 row (oy = tid&15, 11
// active). LDS row stride padded to 17 -> conflict-free.
// Writes x2 (output 1 of the reference) into d_out at offset 1024*256.
// ---------------------------------------------------------------------------
__global__ __launch_bounds__(256) void conv2_kernel(
    const float* __restrict__ x1, const float* __restrict__ w,
    const float* __restrict__ cb, const float* __restrict__ bng,
    const float* __restrict__ bnb, const float* __restrict__ bnm,
    const float* __restrict__ bnv, float* __restrict__ x2out) {
  __shared__ float s_in[32][13][17];   // 28,288 B
  const int b   = blockIdx.x;
  const int tid = threadIdx.x;
  const float* xin = x1 + (size_t)b * (32 * 169);
  for (int i = tid; i < 32 * 169; i += 256) {
    int ic = i / 169;
    int r  = i - ic * 169;
    int yy = r / 13;
    int xx = r - yy * 13;
    s_in[ic][yy][xx] = xin[i];
  }
  __syncthreads();
  const int oy = tid & 15;
  const int g  = tid >> 4;
  if (oy >= 11) return;

  float acc[4][11];
#pragma unroll
  for (int o = 0; o < 4; ++o)
#pragma unroll
    for (int j = 0; j < 11; ++j) acc[o][j] = 0.f;

  const int ocb = g * 4;
  for (int ic = 0; ic < 32; ++ic) {
    float wr[4][9];
#pragma unroll
    for (int o = 0; o < 4; ++o)
#pragma unroll
      for (int k = 0; k < 9; ++k)
        wr[o][k] = w[((size_t)(ocb + o) * 32 + ic) * 9 + k];
#pragma unroll
    for (int ky = 0; ky < 3; ++ky) {
      float rin[13];
#pragma unroll
      for (int j = 0; j < 13; ++j) rin[j] = s_in[ic][oy + ky][j];
#pragma unroll
      for (int ox = 0; ox < 11; ++ox) {
#pragma unroll
        for (int o = 0; o < 4; ++o) {
          acc[o][ox] = fmaf(wr[o][ky*3+2], rin[ox+2],
                       fmaf(wr[o][ky*3+1], rin[ox+1],
                       fmaf(wr[o][ky*3+0], rin[ox+0], acc[o][ox])));
        }
      }
    }
  }

#pragma unroll
  for (int o = 0; o < 4; ++o) {
    const int oc = ocb + o;
    const float bias = cb[oc];
    const float sc = bng[oc] * rsqrtf(bnv[oc] + 1e-5f);
    const float sh = bnb[oc] - bnm[oc] * sc;
    float* op = x2out + ((size_t)b * 64 + oc) * 121 + oy * 11;
#pragma unroll
    for (int ox = 0; ox < 11; ++ox) {
      float v = LEAKY1(acc[o][ox] + bias);
      op[ox] = v * sc + sh;
    }
  }
}

// ---------------------------------------------------------------------------
// Kernel 3: SAM + SGraph + DGraph per batch element. One block per batch.
// ---------------------------------------------------------------------------
__global__ __launch_bounds__(256) void sam_graph_kernel(
    const float* __restrict__ x2,       // [B,64,121]
    const float* __restrict__ fc_sam_w, // [4,64]
    const float* __restrict__ conv_t_w, // [64,64]
    const float* __restrict__ conv_t_b, // [64]
    const float* __restrict__ s_adj_w,  // [4,4]
    const float* __restrict__ s_w_w,    // [64,64]
    const float* __restrict__ s_w_b,    // [64]
    const float* __restrict__ d_co_w,   // [4,128]
    const float* __restrict__ d_co_b,   // [4]
    const float* __restrict__ d_gamma,  // [1]
    const float* __restrict__ d_dw_w,   // [64,64]
    const float* __restrict__ d_dw_b,   // [64]
    float* __restrict__ x6) {           // [B,256]
  __shared__ float s_flat[64][124];
  __shared__ float s_xt[64][124];
  __shared__ float s_mask[4][124];
  __shared__ float s_x3[64][4];
  __shared__ float s_a[64][4];
  __shared__ float s_x4[64][4];
  __shared__ float s_att[64][66];       // energy, then att
  __shared__ float s_xg[64][4];
  __shared__ float s_dadj[4][4];
  __shared__ float s_y[64][4];

  const int b   = blockIdx.x;
  const int tid = threadIdx.x;
  const float* f = x2 + (size_t)b * 7744;

  // stage flat [64][121]
  for (int i = tid; i < 7744; i += 256) {
    int c = i / 121, l = i - c * 121;
    s_flat[c][l] = f[i];
  }
  __syncthreads();

  // mask[n][l] = sigmoid(sum_c fc_sam_w[n][c] * flat[c][l])
  for (int i = tid; i < 4 * 121; i += 256) {
    int n = i / 121, l = i - n * 121;
    float s = 0.f;
    for (int c = 0; c < 64; ++c) s = fmaf(fc_sam_w[n*64 + c], s_flat[c][l], s);
    s_mask[n][l] = 1.f / (1.f + __expf(-s));
  }
  // xt[o][l] = sum_c conv_t_w[o][c] * flat[c][l] + conv_t_b[o]
  for (int i = tid; i < 64 * 121; i += 256) {
    int c = i / 121, l = i - c * 121;
    float s = conv_t_b[c];
    for (int k = 0; k < 64; ++k) s = fmaf(conv_t_w[c*64 + k], s_flat[k][l], s);
    s_xt[c][l] = s;
  }
  __syncthreads();

  // x3[c][n] = sum_l xt[c][l]*mask[n][l]   (exactly 256 outputs)
  {
    int c = tid >> 2, n = tid & 3;
    float s = 0.f;
    for (int l = 0; l < 121; ++l) s = fmaf(s_xt[c][l], s_mask[n][l], s);
    s_x3[c][n] = s;
  }
  __syncthreads();

  // a[f][m] = leaky(sum_n s_adj_w[m][n]*x3[f][n], 0.2)
  {
    int fi = tid >> 2, m = tid & 3;
    float s = 0.f;
#pragma unroll
    for (int n = 0; n < 4; ++n) s = fmaf(s_adj_w[m*4 + n], s_x3[fi][n], s);
    s_a[fi][m] = LEAKY2(s);
  }
  __syncthreads();

  // sg[o][n] = leaky(sum_f s_w_w[o][f]*a[f][n] + s_w_b[o], 0.2); x4 = sg + x3
  {
    int o = tid >> 2, n = tid & 3;
    float s = s_w_b[o];
    for (int ff = 0; ff < 64; ++ff) s = fmaf(s_w_w[o*64 + ff], s_a[ff][n], s);
    s = LEAKY2(s);
    s_x4[o][n] = s + s_x3[o][n];
  }
  __syncthreads();

  // energy[c][d] = sum_n x4[c][n]*x4[d][n]
  for (int i = tid; i < 4096; i += 256) {
    int c = i >> 6, d = i & 63;
    float s = 0.f;
#pragma unroll
    for (int n = 0; n < 4; ++n) s = fmaf(s_x4[c][n], s_x4[d][n], s);
    s_att[c][d] = s;
  }
  __syncthreads();

  // softmax over d of (rowmax - energy)  == exp(rowmin - energy)/sum
  if (tid < 64) {
    int c = tid;
    float mn = 1e30f;
    for (int d = 0; d < 64; ++d) mn = fminf(mn, s_att[c][d]);
    float ssum = 0.f;
    for (int d = 0; d < 64; ++d) {
      float e = __expf(mn - s_att[c][d]);
      s_att[c][d] = e;
      ssum += e;
    }
    float inv = 1.f / ssum;
    for (int d = 0; d < 64; ++d) s_att[c][d] *= inv;
  }
  __syncthreads();

  // out[c][n] = sum_d att[c][d]*x4[d][n]; x_glb = gamma*out + x4
  const float gamma = d_gamma[0];
  {
    int c = tid >> 2, n = tid & 3;
    float s = 0.f;
    for (int d = 0; d < 64; ++d) s = fmaf(s_att[c][d], s_x4[d][n], s);
    s_xg[c][n] = gamma * s + s_x4[c][n];
  }
  __syncthreads();

  // dadj[m][n] = sigmoid(sum_k d_co_w[m][k]*cat[k][n] + d_co_b[m]), cat=[xg;x4]
  if (tid < 16) {
    int m = tid >> 2, n = tid & 3;
    float s = d_co_b[m];
    for (int k = 0; k < 64; ++k) s = fmaf(d_co_w[m*128 + k],      s_xg[k][n], s);
    for (int k = 0; k < 64; ++k) s = fmaf(d_co_w[m*128 + 64 + k], s_x4[k][n], s);
    s_dadj[m][n] = 1.f / (1.f + __expf(-s));
  }
  __syncthreads();

  // y[c][m] = leaky(sum_n x4[c][n]*dadj[n][m], 0.2)
  {
    int c = tid >> 2, m = tid & 3;
    float s = 0.f;
#pragma unroll
    for (int n = 0; n < 4; ++n) s = fmaf(s_x4[c][n], s_dadj[n][m], s);
    s_y[c][m] = LEAKY2(s);
  }
  __syncthreads();

  // y2[o][n] = leaky(sum_f d_dw_w[o][f]*y[f][n] + d_dw_b[o], 0.2); x5 = y2 + x4
  {
    int o = tid >> 2, n = tid & 3;
    float s = d_dw_b[o];
    for (int ff = 0; ff < 64; ++ff) s = fmaf(d_dw_w[o*64 + ff], s_y[ff][n], s);
    s = LEAKY2(s);
    x6[(size_t)b * 256 + tid] = s + s_x4[o][n];
  }
}

// ---------------------------------------------------------------------------
extern "C" void kernel_launch(void* const* d_in, const int* in_sizes, int n_in,
                              void* d_out, int out_size, void* d_ws, size_t ws_size,
                              hipStream_t stream) {
  const float* x     = (const float*)d_in[0];
  const float* c1w   = (const float*)d_in[1];
  const float* c1b   = (const float*)d_in[2];
  const float* bn1g  = (const float*)d_in[3];
  const float* bn1b  = (const float*)d_in[4];
  const float* bn1m  = (const float*)d_in[5];
  const float* bn1v  = (const float*)d_in[6];
  const float* c2w   = (const float*)d_in[7];
  const float* c2b   = (const float*)d_in[8];
  const float* bn2g  = (const float*)d_in[9];
  const float* bn2b  = (const float*)d_in[10];
  const float* bn2m  = (const float*)d_in[11];
  const float* bn2v  = (const float*)d_in[12];
  const float* fcw   = (const float*)d_in[13];
  const float* ctw   = (const float*)d_in[14];
  const float* ctb   = (const float*)d_in[15];
  const float* sadj  = (const float*)d_in[16];
  const float* sww   = (const float*)d_in[17];
  const float* swb   = (const float*)d_in[18];
  const float* dcow  = (const float*)d_in[19];
  const float* dcob  = (const float*)d_in[20];
  const float* dgam  = (const float*)d_in[21];
  const float* ddww  = (const float*)d_in[22];
  const float* ddwb  = (const float*)d_in[23];

  float* out = (float*)d_out;
  float* x6  = out;                      // [1024,256]
  float* x2  = out + (size_t)1024 * 256; // [1024,64,121]
  float* x1  = (float*)d_ws;             // [1024,32,169]  (22.2 MB scratch)

  conv1_kernel<<<1024, 256, 0, stream>>>(x, c1w, c1b, bn1g, bn1b, bn1m, bn1v, x1);
  conv2_kernel<<<1024, 256, 0, stream>>>(x1, c2w, c2b, bn2g, bn2b, bn2m, bn2v, x2);
  sam_graph_kernel<<<1024, 256, 0, stream>>>(x2, fcw, ctw, ctb, sadj, sww, swb,
                                             dcow, dcob, dgam, ddww, ddwb, x6);
}

// Round 4
// 588.540 us; speedup vs baseline: 1.5446x; 1.0624x over previous
//
#include <hip/hip_runtime.h>
#include <math.h>

typedef __bf16 bf16x8 __attribute__((ext_vector_type(8)));
typedef float f32x4 __attribute__((ext_vector_type(4)));

#define LEAKY1(v) ((v) >= 0.f ? (v) : 0.01f*(v))
#define LEAKY2(v) ((v) >= 0.f ? (v) : 0.2f*(v))

__device__ __forceinline__ unsigned short f2bf(float f) {
  unsigned u = __float_as_uint(f);
  u += 0x7FFFu + ((u >> 16) & 1u);   // round-to-nearest-even
  return (unsigned short)(u >> 16);
}

// ---------------------------------------------------------------------------
// Weight prep: conv1_w [32][103][3][3] fp32 -> W1 bf16 [tap=9][oc=32][k=128]
// (k = ic, zero-padded 103->128). Runs every launch (cheap, idempotent).
// ---------------------------------------------------------------------------
__global__ void w1prep_kernel(const float* __restrict__ w, unsigned short* __restrict__ w1p) {
  int idx = blockIdx.x * 256 + threadIdx.x;        // < 9*32*128 = 36864
  if (idx >= 9 * 32 * 128) return;
  int tap = idx >> 12;            // /4096
  int rem = idx & 4095;
  int oc  = rem >> 7;
  int k   = rem & 127;
  int ky = tap / 3, kx = tap - ky * 3;
  unsigned short v = 0;
  if (k < 103) v = f2bf(w[((oc * 103 + k) * 3 + ky) * 3 + kx]);
  w1p[idx] = v;
}

// conv2_w [64][32][3][3] fp32 -> W2 bf16 [tap=9][oc=64][k=32]
__global__ void w2prep_kernel(const float* __restrict__ w, unsigned short* __restrict__ w2p) {
  int idx = blockIdx.x * 256 + threadIdx.x;        // < 9*64*32 = 18432
  if (idx >= 9 * 64 * 32) return;
  int tap = idx >> 11;            // /2048
  int rem = idx & 2047;
  int oc  = rem >> 5;
  int k   = rem & 31;
  int ky = tap / 3, kx = tap - ky * 3;
  w2p[idx] = f2bf(w[((oc * 32 + k) * 3 + ky) * 3 + kx]);
}

// ---------------------------------------------------------------------------
// conv1 via MFMA: per batch, out[32oc][169px] = sum over 9 taps of
// W_tap[32x128k] * img_shift[128k x px]. Image in LDS as [y15][x15][ic104]
// bf16 (pixel stride 208 B -> uniform bank spread). 4 waves x (2 m-tiles x
// 3 n-tiles of 16). Epilogue: +bias, leaky(0.01), BN; store bf16 to
// x1g[b][pix][32ic] (= conv2's staging layout).
// ---------------------------------------------------------------------------
__global__ __launch_bounds__(256) void conv1_mfma(
    const float* __restrict__ x, const unsigned short* __restrict__ w1p,
    const float* __restrict__ cb, const float* __restrict__ bng,
    const float* __restrict__ bnb, const float* __restrict__ bnm,
    const float* __restrict__ bnv, unsigned short* __restrict__ x1g) {
  __shared__ __align__(16) unsigned short im[23448];  // 15*15*104 + 48 guard
  const int b_  = blockIdx.x;
  const int tid = threadIdx.x;
  const float* xin = x + (size_t)b_ * 23175;          // 103*225

  // zero ic-pad slot (103) and tail guard
  for (int i = tid; i < 225; i += 256) im[i * 104 + 103] = 0;
  for (int i = tid; i < 48; i += 256) im[23400 + i] = 0;

  // stage: lane = ic (write-conflict-free; global reads are L2-absorbed)
  {
    int ic = -1, odd = 0;
    if (tid < 103) ic = tid;
    else if (tid >= 128 && tid < 231) { ic = tid - 128; odd = 1; }
    if (ic >= 0) {
      const float* src = xin + (size_t)ic * 225;
      for (int q = 0; q < 113; ++q) {
        int p = 2 * q + odd;
        if (p < 225) im[p * 104 + ic] = f2bf(src[p]);
      }
    }
  }
  __syncthreads();

  const int lane = tid & 63, wid = tid >> 6;
  const int ln = lane & 15, kg = lane >> 4;

  int rb[3], pv[3];
#pragma unroll
  for (int nt = 0; nt < 3; ++nt) {
    int pix = (wid * 3 + nt) * 16 + ln;
    pv[nt] = (pix < 169);
    if (pix >= 169) pix = 0;
    int oy = pix / 13, ox = pix - oy * 13;
    rb[nt] = (oy * 15 + ox) * 208 + kg * 16;   // byte offset incl. k-group
  }

  f32x4 acc[2][3];
#pragma unroll
  for (int mt = 0; mt < 2; ++mt)
#pragma unroll
    for (int nt = 0; nt < 3; ++nt) acc[mt][nt] = (f32x4){0.f, 0.f, 0.f, 0.f};

  const unsigned short* wbase = w1p + (size_t)ln * 128 + kg * 8;
  const char* imb = (const char*)im;

  for (int ky = 0; ky < 3; ++ky) {
    for (int kx = 0; kx < 3; ++kx) {
      const int tap = ky * 3 + kx;
      const int tsh = (ky * 15 + kx) * 208;
      const unsigned short* wp = wbase + tap * 4096;
      bf16x8 a0[4], a1[4];
#pragma unroll
      for (int kt = 0; kt < 4; ++kt) {
        a0[kt] = *(const bf16x8*)(wp + kt * 32);
        a1[kt] = *(const bf16x8*)(wp + 2048 + kt * 32);  // oc+16
      }
#pragma unroll
      for (int kt = 0; kt < 4; ++kt) {
#pragma unroll
        for (int nt = 0; nt < 3; ++nt) {
          bf16x8 bv = *(const bf16x8*)(imb + rb[nt] + tsh + kt * 64);
          acc[0][nt] = __builtin_amdgcn_mfma_f32_16x16x32_bf16(a0[kt], bv, acc[0][nt], 0, 0, 0);
          acc[1][nt] = __builtin_amdgcn_mfma_f32_16x16x32_bf16(a1[kt], bv, acc[1][nt], 0, 0, 0);
        }
      }
    }
  }

  // epilogue: bias -> leaky(0.01) -> BN -> bf16 store [b][pix][oc]
#pragma unroll
  for (int mt = 0; mt < 2; ++mt) {
#pragma unroll
    for (int nt = 0; nt < 3; ++nt) {
      if (!pv[nt]) continue;
      int pix = (wid * 3 + nt) * 16 + ln;
      unsigned short* dst = x1g + ((size_t)b_ * 169 + pix) * 32;
      f32x4 a = acc[mt][nt];
#pragma unroll
      for (int r = 0; r < 4; ++r) {
        int oc = mt * 16 + kg * 4 + r;
        float val = a[r] + cb[oc];
        val = LEAKY1(val);
        float sc = bng[oc] * rsqrtf(bnv[oc] + 1e-5f);
        float sh = bnb[oc] - bnm[oc] * sc;
        dst[oc] = f2bf(val * sc + sh);
      }
    }
  }
}

// ---------------------------------------------------------------------------
// conv2 via MFMA: per batch, out[64oc][121px] = sum over 9 taps of
// W2_tap[64x32] * x1_shift[32 x px]. LDS [13][13][40] bf16 (80 B stride).
// 4 waves x (4 m-tiles x 2 n-tiles). Epilogue: bias/leaky/BN -> fp32 x2.
// ---------------------------------------------------------------------------
__global__ __launch_bounds__(256) void conv2_mfma(
    const unsigned short* __restrict__ x1g, const unsigned short* __restrict__ w2p,
    const float* __restrict__ cb, const float* __restrict__ bng,
    const float* __restrict__ bnb, const float* __restrict__ bnm,
    const float* __restrict__ bnv, float* __restrict__ x2out) {
  __shared__ __align__(16) unsigned short im2[6760];  // 13*13*40
  const int b_  = blockIdx.x;
  const int tid = threadIdx.x;

  // stage x1g[b][pix][32] -> im2[pix][40] (16B vector copies)
  for (int i = tid; i < 676; i += 256) {   // 169 * 4
    int pix = i >> 2, icg = i & 3;
    const uint4* src = (const uint4*)(x1g + ((size_t)b_ * 169 + pix) * 32 + icg * 8);
    *(uint4*)(im2 + pix * 40 + icg * 8) = *src;
  }
  __syncthreads();

  const int lane = tid & 63, wid = tid >> 6;
  const int ln = lane & 15, kg = lane >> 4;

  int rb[2], pv[2];
#pragma unroll
  for (int nt = 0; nt < 2; ++nt) {
    int pix = (wid * 2 + nt) * 16 + ln;
    pv[nt] = (pix < 121);
    if (pix >= 121) pix = 0;
    int oy = pix / 11, ox = pix - oy * 11;
    rb[nt] = (oy * 13 + ox) * 80 + kg * 16;
  }

  f32x4 acc[4][2];
#pragma unroll
  for (int mt = 0; mt < 4; ++mt)
#pragma unroll
    for (int nt = 0; nt < 2; ++nt) acc[mt][nt] = (f32x4){0.f, 0.f, 0.f, 0.f};

  const unsigned short* wbase = w2p + (size_t)ln * 32 + kg * 8;
  const char* imb = (const char*)im2;

  for (int ky = 0; ky < 3; ++ky) {
    for (int kx = 0; kx < 3; ++kx) {
      const int tap = ky * 3 + kx;
      const int tsh = (ky * 13 + kx) * 80;
      const unsigned short* wp = wbase + tap * 2048;
      bf16x8 a[4];
#pragma unroll
      for (int mt = 0; mt < 4; ++mt) a[mt] = *(const bf16x8*)(wp + mt * 512);
#pragma unroll
      for (int nt = 0; nt < 2; ++nt) {
        bf16x8 bv = *(const bf16x8*)(imb + rb[nt] + tsh);
#pragma unroll
        for (int mt = 0; mt < 4; ++mt)
          acc[mt][nt] = __builtin_amdgcn_mfma_f32_16x16x32_bf16(a[mt], bv, acc[mt][nt], 0, 0, 0);
      }
    }
  }

#pragma unroll
  for (int mt = 0; mt < 4; ++mt) {
#pragma unroll
    for (int nt = 0; nt < 2; ++nt) {
      if (!pv[nt]) continue;
      int pix = (wid * 2 + nt) * 16 + ln;
      f32x4 a = acc[mt][nt];
#pragma unroll
      for (int r = 0; r < 4; ++r) {
        int oc = mt * 16 + kg * 4 + r;
        float val = a[r] + cb[oc];
        val = LEAKY1(val);
        float sc = bng[oc] * rsqrtf(bnv[oc] + 1e-5f);
        float sh = bnb[oc] - bnm[oc] * sc;
        x2out[((size_t)b_ * 64 + oc) * 121 + pix] = val * sc + sh;
      }
    }
  }
}

// ---------------------------------------------------------------------------
// Kernel 3: SAM + SGraph + DGraph per batch element. One block per batch.
// ---------------------------------------------------------------------------
__global__ __launch_bounds__(256) void sam_graph_kernel(
    const float* __restrict__ x2,       // [B,64,121]
    const float* __restrict__ fc_sam_w, // [4,64]
    const float* __restrict__ conv_t_w, // [64,64]
    const float* __restrict__ conv_t_b, // [64]
    const float* __restrict__ s_adj_w,  // [4,4]
    const float* __restrict__ s_w_w,    // [64,64]
    const float* __restrict__ s_w_b,    // [64]
    const float* __restrict__ d_co_w,   // [4,128]
    const float* __restrict__ d_co_b,   // [4]
    const float* __restrict__ d_gamma,  // [1]
    const float* __restrict__ d_dw_w,   // [64,64]
    const float* __restrict__ d_dw_b,   // [64]
    float* __restrict__ x6) {           // [B,256]
  __shared__ float s_flat[64][124];
  __shared__ float s_xt[64][124];
  __shared__ float s_mask[4][124];
  __shared__ float s_x3[64][4];
  __shared__ float s_a[64][4];
  __shared__ float s_x4[64][4];
  __shared__ float s_att[64][66];       // energy, then att
  __shared__ float s_xg[64][4];
  __shared__ float s_dadj[4][4];
  __shared__ float s_y[64][4];

  const int b   = blockIdx.x;
  const int tid = threadIdx.x;
  const float* f = x2 + (size_t)b * 7744;

  for (int i = tid; i < 7744; i += 256) {
    int c = i / 121, l = i - c * 121;
    s_flat[c][l] = f[i];
  }
  __syncthreads();

  for (int i = tid; i < 4 * 121; i += 256) {
    int n = i / 121, l = i - n * 121;
    float s = 0.f;
    for (int c = 0; c < 64; ++c) s = fmaf(fc_sam_w[n*64 + c], s_flat[c][l], s);
    s_mask[n][l] = 1.f / (1.f + __expf(-s));
  }
  for (int i = tid; i < 64 * 121; i += 256) {
    int c = i / 121, l = i - c * 121;
    float s = conv_t_b[c];
    for (int k = 0; k < 64; ++k) s = fmaf(conv_t_w[c*64 + k], s_flat[k][l], s);
    s_xt[c][l] = s;
  }
  __syncthreads();

  {
    int c = tid >> 2, n = tid & 3;
    float s = 0.f;
    for (int l = 0; l < 121; ++l) s = fmaf(s_xt[c][l], s_mask[n][l], s);
    s_x3[c][n] = s;
  }
  __syncthreads();

  {
    int fi = tid >> 2, m = tid & 3;
    float s = 0.f;
#pragma unroll
    for (int n = 0; n < 4; ++n) s = fmaf(s_adj_w[m*4 + n], s_x3[fi][n], s);
    s_a[fi][m] = LEAKY2(s);
  }
  __syncthreads();

  {
    int o = tid >> 2, n = tid & 3;
    float s = s_w_b[o];
    for (int ff = 0; ff < 64; ++ff) s = fmaf(s_w_w[o*64 + ff], s_a[ff][n], s);
    s = LEAKY2(s);
    s_x4[o][n] = s + s_x3[o][n];
  }
  __syncthreads();

  for (int i = tid; i < 4096; i += 256) {
    int c = i >> 6, d = i & 63;
    float s = 0.f;
#pragma unroll
    for (int n = 0; n < 4; ++n) s = fmaf(s_x4[c][n], s_x4[d][n], s);
    s_att[c][d] = s;
  }
  __syncthreads();

  if (tid < 64) {
    int c = tid;
    float mn = 1e30f;
    for (int d = 0; d < 64; ++d) mn = fminf(mn, s_att[c][d]);
    float ssum = 0.f;
    for (int d = 0; d < 64; ++d) {
      float e = __expf(mn - s_att[c][d]);
      s_att[c][d] = e;
      ssum += e;
    }
    float inv = 1.f / ssum;
    for (int d = 0; d < 64; ++d) s_att[c][d] *= inv;
  }
  __syncthreads();

  const float gamma = d_gamma[0];
  {
    int c = tid >> 2, n = tid & 3;
    float s = 0.f;
    for (int d = 0; d < 64; ++d) s = fmaf(s_att[c][d], s_x4[d][n], s);
    s_xg[c][n] = gamma * s + s_x4[c][n];
  }
  __syncthreads();

  if (tid < 16) {
    int m = tid >> 2, n = tid & 3;
    float s = d_co_b[m];
    for (int k = 0; k < 64; ++k) s = fmaf(d_co_w[m*128 + k],      s_xg[k][n], s);
    for (int k = 0; k < 64; ++k) s = fmaf(d_co_w[m*128 + 64 + k], s_x4[k][n], s);
    s_dadj[m][n] = 1.f / (1.f + __expf(-s));
  }
  __syncthreads();

  {
    int c = tid >> 2, m = tid & 3;
    float s = 0.f;
#pragma unroll
    for (int n = 0; n < 4; ++n) s = fmaf(s_x4[c][n], s_dadj[n][m], s);
    s_y[c][m] = LEAKY2(s);
  }
  __syncthreads();

  {
    int o = tid >> 2, n = tid & 3;
    float s = d_dw_b[o];
    for (int ff = 0; ff < 64; ++ff) s = fmaf(d_dw_w[o*64 + ff], s_y[ff][n], s);
    s = LEAKY2(s);
    x6[(size_t)b * 256 + tid] = s + s_x4[o][n];
  }
}

// ---------------------------------------------------------------------------
extern "C" void kernel_launch(void* const* d_in, const int* in_sizes, int n_in,
                              void* d_out, int out_size, void* d_ws, size_t ws_size,
                              hipStream_t stream) {
  const float* x     = (const float*)d_in[0];
  const float* c1w   = (const float*)d_in[1];
  const float* c1b   = (const float*)d_in[2];
  const float* bn1g  = (const float*)d_in[3];
  const float* bn1b  = (const float*)d_in[4];
  const float* bn1m  = (const float*)d_in[5];
  const float* bn1v  = (const float*)d_in[6];
  const float* c2w   = (const float*)d_in[7];
  const float* c2b   = (const float*)d_in[8];
  const float* bn2g  = (const float*)d_in[9];
  const float* bn2b  = (const float*)d_in[10];
  const float* bn2m  = (const float*)d_in[11];
  const float* bn2v  = (const float*)d_in[12];
  const float* fcw   = (const float*)d_in[13];
  const float* ctw   = (const float*)d_in[14];
  const float* ctb   = (const float*)d_in[15];
  const float* sadj  = (const float*)d_in[16];
  const float* sww   = (const float*)d_in[17];
  const float* swb   = (const float*)d_in[18];
  const float* dcow  = (const float*)d_in[19];
  const float* dcob  = (const float*)d_in[20];
  const float* dgam  = (const float*)d_in[21];
  const float* ddww  = (const float*)d_in[22];
  const float* ddwb  = (const float*)d_in[23];

  float* out = (float*)d_out;
  float* x6  = out;                      // [1024,256]
  float* x2  = out + (size_t)1024 * 256; // [1024,64,121]

  unsigned short* x1g = (unsigned short*)d_ws;       // [1024][169][32] bf16
  unsigned short* w1p = x1g + (size_t)1024 * 169 * 32; // [9][32][128] bf16
  unsigned short* w2p = w1p + 9 * 32 * 128;            // [9][64][32] bf16

  w1prep_kernel<<<144, 256, 0, stream>>>(c1w, w1p);
  w2prep_kernel<<<72, 256, 0, stream>>>(c2w, w2p);
  conv1_mfma<<<1024, 256, 0, stream>>>(x, w1p, c1b, bn1g, bn1b, bn1m, bn1v, x1g);
  conv2_mfma<<<1024, 256, 0, stream>>>(x1g, w2p, c2b, bn2g, bn2b, bn2m, bn2v, x2);
  sam_graph_kernel<<<1024, 256, 0, stream>>>(x2, fcw, ctw, ctb, sadj, sww, swb,
                                             dcow, dcob, dgam, ddww, ddwb, x6);
}

// Round 5
// 307.279 us; speedup vs baseline: 2.9585x; 1.9153x over previous
//
#include <hip/hip_runtime.h>
#include <math.h>

typedef __bf16 bf16x8 __attribute__((ext_vector_type(8)));
typedef float f32x4 __attribute__((ext_vector_type(4)));

#define LEAKY1(v) ((v) >= 0.f ? (v) : 0.01f*(v))
#define LEAKY2(v) ((v) >= 0.f ? (v) : 0.2f*(v))

__device__ __forceinline__ unsigned short f2bf(float f) {
  unsigned u = __float_as_uint(f);
  u += 0x7FFFu + ((u >> 16) & 1u);   // round-to-nearest-even
  return (unsigned short)(u >> 16);
}

// ---------------------------------------------------------------------------
// Weight prep: conv1_w [32][103][3][3] fp32 -> W1 bf16 [tap=9][oc=32][k=128]
// ---------------------------------------------------------------------------
__global__ void w1prep_kernel(const float* __restrict__ w, unsigned short* __restrict__ w1p) {
  int idx = blockIdx.x * 256 + threadIdx.x;        // < 9*32*128 = 36864
  if (idx >= 9 * 32 * 128) return;
  int tap = idx >> 12;
  int rem = idx & 4095;
  int oc  = rem >> 7;
  int k   = rem & 127;
  int ky = tap / 3, kx = tap - ky * 3;
  unsigned short v = 0;
  if (k < 103) v = f2bf(w[((oc * 103 + k) * 3 + ky) * 3 + kx]);
  w1p[idx] = v;
}

// conv2_w [64][32][3][3] fp32 -> W2 bf16 [tap=9][oc=64][k=32]
__global__ void w2prep_kernel(const float* __restrict__ w, unsigned short* __restrict__ w2p) {
  int idx = blockIdx.x * 256 + threadIdx.x;        // < 9*64*32 = 18432
  if (idx >= 9 * 64 * 32) return;
  int tap = idx >> 11;
  int rem = idx & 2047;
  int oc  = rem >> 5;
  int k   = rem & 31;
  int ky = tap / 3, kx = tap - ky * 3;
  w2p[idx] = f2bf(w[((oc * 32 + k) * 3 + ky) * 3 + kx]);
}

// W3 bf16 [80][64]: rows 0-63 = conv_t_w, rows 64-67 = fc_sam_w, 68-79 = 0
__global__ void w3prep_kernel(const float* __restrict__ ctw, const float* __restrict__ fcw,
                              unsigned short* __restrict__ w3p) {
  int idx = blockIdx.x * 256 + threadIdx.x;        // < 80*64 = 5120
  if (idx >= 80 * 64) return;
  int row = idx >> 6, c = idx & 63;
  float v = 0.f;
  if (row < 64) v = ctw[row * 64 + c];
  else if (row < 68) v = fcw[(row - 64) * 64 + c];
  w3p[idx] = f2bf(v);
}

// ---------------------------------------------------------------------------
// conv1 via MFMA. Staging: lane = pixel (coalesced global reads), transpose
// write to im[pixel][ic-pad104]. MFMA: 9-tap shifted GEMM, W[32x128k].
// ---------------------------------------------------------------------------
__global__ __launch_bounds__(256) void conv1_mfma(
    const float* __restrict__ x, const unsigned short* __restrict__ w1p,
    const float* __restrict__ cb, const float* __restrict__ bng,
    const float* __restrict__ bnb, const float* __restrict__ bnm,
    const float* __restrict__ bnv, unsigned short* __restrict__ x1g) {
  __shared__ __align__(16) unsigned short im[23448];  // 15*15*104 + 48 guard
  const int b_  = blockIdx.x;
  const int tid = threadIdx.x;
  const float* xin = x + (size_t)b_ * 23175;          // 103*225

  for (int i = tid; i < 225; i += 256) im[i * 104 + 103] = 0;
  for (int i = tid; i < 48; i += 256) im[23400 + i] = 0;

  // coalesced staging: lane = pixel, loop channels (stream 900B/wave/instr)
  if (tid < 225) {
    const float* src = xin + tid;
    unsigned short* dst = im + tid * 104;
#pragma unroll 8
    for (int ic = 0; ic < 103; ++ic) dst[ic] = f2bf(src[(size_t)ic * 225]);
  }
  __syncthreads();

  const int lane = tid & 63, wid = tid >> 6;
  const int ln = lane & 15, kg = lane >> 4;

  int rb[3], pv[3];
#pragma unroll
  for (int nt = 0; nt < 3; ++nt) {
    int pix = (wid * 3 + nt) * 16 + ln;
    pv[nt] = (pix < 169);
    if (pix >= 169) pix = 0;
    int oy = pix / 13, ox = pix - oy * 13;
    rb[nt] = (oy * 15 + ox) * 208 + kg * 16;
  }

  f32x4 acc[2][3];
#pragma unroll
  for (int mt = 0; mt < 2; ++mt)
#pragma unroll
    for (int nt = 0; nt < 3; ++nt) acc[mt][nt] = (f32x4){0.f, 0.f, 0.f, 0.f};

  const unsigned short* wbase = w1p + (size_t)ln * 128 + kg * 8;
  const char* imb = (const char*)im;

  for (int ky = 0; ky < 3; ++ky) {
    for (int kx = 0; kx < 3; ++kx) {
      const int tap = ky * 3 + kx;
      const int tsh = (ky * 15 + kx) * 208;
      const unsigned short* wp = wbase + tap * 4096;
      bf16x8 a0[4], a1[4];
#pragma unroll
      for (int kt = 0; kt < 4; ++kt) {
        a0[kt] = *(const bf16x8*)(wp + kt * 32);
        a1[kt] = *(const bf16x8*)(wp + 2048 + kt * 32);
      }
#pragma unroll
      for (int kt = 0; kt < 4; ++kt) {
#pragma unroll
        for (int nt = 0; nt < 3; ++nt) {
          bf16x8 bv = *(const bf16x8*)(imb + rb[nt] + tsh + kt * 64);
          acc[0][nt] = __builtin_amdgcn_mfma_f32_16x16x32_bf16(a0[kt], bv, acc[0][nt], 0, 0, 0);
          acc[1][nt] = __builtin_amdgcn_mfma_f32_16x16x32_bf16(a1[kt], bv, acc[1][nt], 0, 0, 0);
        }
      }
    }
  }

#pragma unroll
  for (int mt = 0; mt < 2; ++mt) {
#pragma unroll
    for (int nt = 0; nt < 3; ++nt) {
      if (!pv[nt]) continue;
      int pix = (wid * 3 + nt) * 16 + ln;
      unsigned short* dst = x1g + ((size_t)b_ * 169 + pix) * 32;
      f32x4 a = acc[mt][nt];
#pragma unroll
      for (int r = 0; r < 4; ++r) {
        int oc = mt * 16 + kg * 4 + r;
        float val = a[r] + cb[oc];
        val = LEAKY1(val);
        float sc = bng[oc] * rsqrtf(bnv[oc] + 1e-5f);
        float sh = bnb[oc] - bnm[oc] * sc;
        dst[oc] = f2bf(val * sc + sh);
      }
    }
  }
}

// ---------------------------------------------------------------------------
// conv2 via MFMA (unchanged).
// ---------------------------------------------------------------------------
__global__ __launch_bounds__(256) void conv2_mfma(
    const unsigned short* __restrict__ x1g, const unsigned short* __restrict__ w2p,
    const float* __restrict__ cb, const float* __restrict__ bng,
    const float* __restrict__ bnb, const float* __restrict__ bnm,
    const float* __restrict__ bnv, float* __restrict__ x2out) {
  __shared__ __align__(16) unsigned short im2[6760];  // 13*13*40
  const int b_  = blockIdx.x;
  const int tid = threadIdx.x;

  for (int i = tid; i < 676; i += 256) {
    int pix = i >> 2, icg = i & 3;
    const uint4* src = (const uint4*)(x1g + ((size_t)b_ * 169 + pix) * 32 + icg * 8);
    *(uint4*)(im2 + pix * 40 + icg * 8) = *src;
  }
  __syncthreads();

  const int lane = tid & 63, wid = tid >> 6;
  const int ln = lane & 15, kg = lane >> 4;

  int rb[2], pv[2];
#pragma unroll
  for (int nt = 0; nt < 2; ++nt) {
    int pix = (wid * 2 + nt) * 16 + ln;
    pv[nt] = (pix < 121);
    if (pix >= 121) pix = 0;
    int oy = pix / 11, ox = pix - oy * 11;
    rb[nt] = (oy * 13 + ox) * 80 + kg * 16;
  }

  f32x4 acc[4][2];
#pragma unroll
  for (int mt = 0; mt < 4; ++mt)
#pragma unroll
    for (int nt = 0; nt < 2; ++nt) acc[mt][nt] = (f32x4){0.f, 0.f, 0.f, 0.f};

  const unsigned short* wbase = w2p + (size_t)ln * 32 + kg * 8;
  const char* imb = (const char*)im2;

  for (int ky = 0; ky < 3; ++ky) {
    for (int kx = 0; kx < 3; ++kx) {
      const int tap = ky * 3 + kx;
      const int tsh = (ky * 13 + kx) * 80;
      const unsigned short* wp = wbase + tap * 2048;
      bf16x8 a[4];
#pragma unroll
      for (int mt = 0; mt < 4; ++mt) a[mt] = *(const bf16x8*)(wp + mt * 512);
#pragma unroll
      for (int nt = 0; nt < 2; ++nt) {
        bf16x8 bv = *(const bf16x8*)(imb + rb[nt] + tsh);
#pragma unroll
        for (int mt = 0; mt < 4; ++mt)
          acc[mt][nt] = __builtin_amdgcn_mfma_f32_16x16x32_bf16(a[mt], bv, acc[mt][nt], 0, 0, 0);
      }
    }
  }

#pragma unroll
  for (int mt = 0; mt < 4; ++mt) {
#pragma unroll
    for (int nt = 0; nt < 2; ++nt) {
      if (!pv[nt]) continue;
      int pix = (wid * 2 + nt) * 16 + ln;
      f32x4 a = acc[mt][nt];
#pragma unroll
      for (int r = 0; r < 4; ++r) {
        int oc = mt * 16 + kg * 4 + r;
        float val = a[r] + cb[oc];
        val = LEAKY1(val);
        float sc = bng[oc] * rsqrtf(bnv[oc] + 1e-5f);
        float sh = bnb[oc] - bnm[oc] * sc;
        x2out[((size_t)b_ * 64 + oc) * 121 + pix] = val * sc + sh;
      }
    }
  }
}

// ---------------------------------------------------------------------------
// Kernel 3: SAM + graphs. xt+mask and x3 via MFMA; rest fp32 VALU.
// ---------------------------------------------------------------------------
__global__ __launch_bounds__(256) void sam_graph_kernel(
    const float* __restrict__ x2,       // [B,64,121]
    const unsigned short* __restrict__ w3p, // [80][64] bf16 (ctw;fcw;0)
    const float* __restrict__ conv_t_b, // [64]
    const float* __restrict__ s_adj_w,  // [4,4]
    const float* __restrict__ s_w_w,    // [64,64]
    const float* __restrict__ s_w_b,    // [64]
    const float* __restrict__ d_co_w,   // [4,128]
    const float* __restrict__ d_co_b,   // [4]
    const float* __restrict__ d_gamma,  // [1]
    const float* __restrict__ d_dw_w,   // [64,64]
    const float* __restrict__ d_dw_b,   // [64]
    float* __restrict__ x6) {           // [B,256]
  __shared__ __align__(16) unsigned short s_flatT[128][72]; // [l][c] bf16
  __shared__ __align__(16) unsigned short s_xt[64][136];    // [c][l] bf16 (+bias)
  __shared__ __align__(16) unsigned short s_mask[16][136];  // [n][l] bf16 sigmoid
  __shared__ float s_x3[64][4];
  __shared__ float s_a[64][4];
  __shared__ float s_x4[64][4];
  __shared__ float s_att[64][66];
  __shared__ float s_xg[64][4];
  __shared__ float s_dadj[4][4];
  __shared__ float s_y[64][4];

  const int b   = blockIdx.x;
  const int tid = threadIdx.x;
  const float* f = x2 + (size_t)b * 7744;

  // zero pads: flatT rows 121-127; whole s_mask
  for (int i = tid; i < 7 * 72; i += 256) s_flatT[121 + i / 72][i % 72] = 0;
  for (int i = tid; i < 16 * 136; i += 256) (&s_mask[0][0])[i] = 0;

  // stage flat^T: [c][l] fp32 global -> [l][c] bf16 LDS (coalesced reads)
  for (int i = tid; i < 7744; i += 256) {
    int c = i / 121, l = i - c * 121;
    s_flatT[l][c] = f2bf(f[i]);
  }
  __syncthreads();

  const int lane = tid & 63, wid = tid >> 6;
  const int ln = lane & 15, kg = lane >> 4;

  // GEMM1: D[80][128] = W3[80x64] * flatT'[64x128]; rows 0-63 = xt (+bias),
  // rows 64-67 -> sigmoid -> mask. 40 tiles, 10 per wave.
  for (int t = wid * 10; t < wid * 10 + 10; ++t) {
    const int mt = t >> 3, nt = t & 7;
    f32x4 acc = (f32x4){0.f, 0.f, 0.f, 0.f};
#pragma unroll
    for (int k0 = 0; k0 < 64; k0 += 32) {
      bf16x8 af = *(const bf16x8*)(w3p + (mt * 16 + ln) * 64 + k0 + kg * 8);
      bf16x8 bf_ = *(const bf16x8*)(&s_flatT[nt * 16 + ln][k0 + kg * 8]);
      acc = __builtin_amdgcn_mfma_f32_16x16x32_bf16(af, bf_, acc, 0, 0, 0);
    }
    const int l = nt * 16 + ln;
#pragma unroll
    for (int r = 0; r < 4; ++r) {
      int row = mt * 16 + kg * 4 + r;
      if (row < 64) s_xt[row][l] = f2bf(acc[r] + conv_t_b[row]);
      else if (row < 68) s_mask[row - 64][l] = f2bf(1.f / (1.f + __expf(-acc[r])));
    }
  }
  __syncthreads();
  // mask cols 121-127 got sigmoid(0)=0.5 from zero-padded flat rows: re-zero
  if (tid < 28) s_mask[tid / 7][121 + tid % 7] = 0;
  __syncthreads();

  // GEMM2: x3[64][4] = xt[64x128l] * mask^T[128x16n]; wave = m-tile.
  {
    f32x4 acc = (f32x4){0.f, 0.f, 0.f, 0.f};
#pragma unroll
    for (int k0 = 0; k0 < 128; k0 += 32) {
      bf16x8 af = *(const bf16x8*)(&s_xt[wid * 16 + ln][k0 + kg * 8]);
      bf16x8 bf_ = *(const bf16x8*)(&s_mask[ln][k0 + kg * 8]);
      acc = __builtin_amdgcn_mfma_f32_16x16x32_bf16(af, bf_, acc, 0, 0, 0);
    }
    if (ln < 4) {
#pragma unroll
      for (int r = 0; r < 4; ++r) s_x3[wid * 16 + kg * 4 + r][ln] = acc[r];
    }
  }
  __syncthreads();

  // a[f][m] = leaky(sum_n s_adj_w[m][n]*x3[f][n], 0.2)
  {
    int fi = tid >> 2, m = tid & 3;
    float s = 0.f;
#pragma unroll
    for (int n = 0; n < 4; ++n) s = fmaf(s_adj_w[m * 4 + n], s_x3[fi][n], s);
    s_a[fi][m] = LEAKY2(s);
  }
  __syncthreads();

  // sg[o][n] = leaky(sum_f s_w_w[o][f]*a[f][n] + s_w_b[o], 0.2); x4 = sg + x3
  {
    int o = tid >> 2, n = tid & 3;
    float s = s_w_b[o];
    for (int ff = 0; ff < 64; ++ff) s = fmaf(s_w_w[o * 64 + ff], s_a[ff][n], s);
    s = LEAKY2(s);
    s_x4[o][n] = s + s_x3[o][n];
  }
  __syncthreads();

  // energy[c][d] = sum_n x4[c][n]*x4[d][n]
  for (int i = tid; i < 4096; i += 256) {
    int c = i >> 6, d = i & 63;
    float s = 0.f;
#pragma unroll
    for (int n = 0; n < 4; ++n) s = fmaf(s_x4[c][n], s_x4[d][n], s);
    s_att[c][d] = s;
  }
  __syncthreads();

  // softmax of (rowmax - energy) over d == exp(rowmin - energy)/sum
  if (tid < 64) {
    int c = tid;
    float mn = 1e30f;
    for (int d = 0; d < 64; ++d) mn = fminf(mn, s_att[c][d]);
    float ssum = 0.f;
    for (int d = 0; d < 64; ++d) {
      float e = __expf(mn - s_att[c][d]);
      s_att[c][d] = e;
      ssum += e;
    }
    float inv = 1.f / ssum;
    for (int d = 0; d < 64; ++d) s_att[c][d] *= inv;
  }
  __syncthreads();

  const float gamma = d_gamma[0];
  {
    int c = tid >> 2, n = tid & 3;
    float s = 0.f;
    for (int d = 0; d < 64; ++d) s = fmaf(s_att[c][d], s_x4[d][n], s);
    s_xg[c][n] = gamma * s + s_x4[c][n];
  }
  __syncthreads();

  if (tid < 16) {
    int m = tid >> 2, n = tid & 3;
    float s = d_co_b[m];
    for (int k = 0; k < 64; ++k) s = fmaf(d_co_w[m * 128 + k],      s_xg[k][n], s);
    for (int k = 0; k < 64; ++k) s = fmaf(d_co_w[m * 128 + 64 + k], s_x4[k][n], s);
    s_dadj[m][n] = 1.f / (1.f + __expf(-s));
  }
  __syncthreads();

  {
    int c = tid >> 2, m = tid & 3;
    float s = 0.f;
#pragma unroll
    for (int n = 0; n < 4; ++n) s = fmaf(s_x4[c][n], s_dadj[n][m], s);
    s_y[c][m] = LEAKY2(s);
  }
  __syncthreads();

  {
    int o = tid >> 2, n = tid & 3;
    float s = d_dw_b[o];
    for (int ff = 0; ff < 64; ++ff) s = fmaf(d_dw_w[o * 64 + ff], s_y[ff][n], s);
    s = LEAKY2(s);
    x6[(size_t)b * 256 + tid] = s + s_x4[o][n];
  }
}

// ---------------------------------------------------------------------------
extern "C" void kernel_launch(void* const* d_in, const int* in_sizes, int n_in,
                              void* d_out, int out_size, void* d_ws, size_t ws_size,
                              hipStream_t stream) {
  const float* x     = (const float*)d_in[0];
  const float* c1w   = (const float*)d_in[1];
  const float* c1b   = (const float*)d_in[2];
  const float* bn1g  = (const float*)d_in[3];
  const float* bn1b  = (const float*)d_in[4];
  const float* bn1m  = (const float*)d_in[5];
  const float* bn1v  = (const float*)d_in[6];
  const float* c2w   = (const float*)d_in[7];
  const float* c2b   = (const float*)d_in[8];
  const float* bn2g  = (const float*)d_in[9];
  const float* bn2b  = (const float*)d_in[10];
  const float* bn2m  = (const float*)d_in[11];
  const float* bn2v  = (const float*)d_in[12];
  const float* fcw   = (const float*)d_in[13];
  const float* ctw   = (const float*)d_in[14];
  const float* ctb   = (const float*)d_in[15];
  const float* sadj  = (const float*)d_in[16];
  const float* sww   = (const float*)d_in[17];
  const float* swb   = (const float*)d_in[18];
  const float* dcow  = (const float*)d_in[19];
  const float* dcob  = (const float*)d_in[20];
  const float* dgam  = (const float*)d_in[21];
  const float* ddww  = (const float*)d_in[22];
  const float* ddwb  = (const float*)d_in[23];

  float* out = (float*)d_out;
  float* x6  = out;                      // [1024,256]
  float* x2  = out + (size_t)1024 * 256; // [1024,64,121]

  unsigned short* x1g = (unsigned short*)d_ws;         // [1024][169][32] bf16
  unsigned short* w1p = x1g + (size_t)1024 * 169 * 32; // [9][32][128]
  unsigned short* w2p = w1p + 9 * 32 * 128;            // [9][64][32]
  unsigned short* w3p = w2p + 9 * 64 * 32;             // [80][64]

  w1prep_kernel<<<144, 256, 0, stream>>>(c1w, w1p);
  w2prep_kernel<<<72, 256, 0, stream>>>(c2w, w2p);
  w3prep_kernel<<<20, 256, 0, stream>>>(ctw, fcw, w3p);
  conv1_mfma<<<1024, 256, 0, stream>>>(x, w1p, c1b, bn1g, bn1b, bn1m, bn1v, x1g);
  conv2_mfma<<<1024, 256, 0, stream>>>(x1g, w2p, c2b, bn2g, bn2b, bn2m, bn2v, x2);
  sam_graph_kernel<<<1024, 256, 0, stream>>>(x2, w3p, ctb, sadj, sww, swb,
                                             dcow, dcob, dgam, ddww, ddwb, x6);
}

// Round 7
// 285.875 us; speedup vs baseline: 3.1800x; 1.0749x over previous
//
#include <hip/hip_runtime.h>
#include <math.h>

typedef __bf16 bf16x8 __attribute__((ext_vector_type(8)));
typedef float f32x4 __attribute__((ext_vector_type(4)));

#define LEAKY1(v) ((v) >= 0.f ? (v) : 0.01f*(v))
#define LEAKY2(v) ((v) >= 0.f ? (v) : 0.2f*(v))

__device__ __forceinline__ unsigned short f2bf(float f) {
  unsigned u = __float_as_uint(f);
  u += 0x7FFFu + ((u >> 16) & 1u);   // round-to-nearest-even
  return (unsigned short)(u >> 16);
}

// ---------------------------------------------------------------------------
// Weight prep kernels (idempotent, run each launch)
// ---------------------------------------------------------------------------
// conv1_w [32][103][3][3] fp32 -> W1 bf16 [tap=9][oc=32][k=128]
__global__ void w1prep_kernel(const float* __restrict__ w, unsigned short* __restrict__ w1p) {
  int idx = blockIdx.x * 256 + threadIdx.x;        // < 36864
  if (idx >= 9 * 32 * 128) return;
  int tap = idx >> 12;
  int rem = idx & 4095;
  int oc  = rem >> 7;
  int k   = rem & 127;
  int ky = tap / 3, kx = tap - ky * 3;
  unsigned short v = 0;
  if (k < 103) v = f2bf(w[((oc * 103 + k) * 3 + ky) * 3 + kx]);
  w1p[idx] = v;
}

// conv2_w [64][32][3][3] fp32 -> W2 bf16 [tap=9][oc=64][k=32]
__global__ void w2prep_kernel(const float* __restrict__ w, unsigned short* __restrict__ w2p) {
  int idx = blockIdx.x * 256 + threadIdx.x;        // < 18432
  if (idx >= 9 * 64 * 32) return;
  int tap = idx >> 11;
  int rem = idx & 2047;
  int oc  = rem >> 5;
  int k   = rem & 31;
  int ky = tap / 3, kx = tap - ky * 3;
  w2p[idx] = f2bf(w[((oc * 32 + k) * 3 + ky) * 3 + kx]);
}

// W3 bf16 [80][64]: rows 0-63 = conv_t_w, rows 64-67 = fc_sam_w, 68-79 = 0
__global__ void w3prep_kernel(const float* __restrict__ ctw, const float* __restrict__ fcw,
                              unsigned short* __restrict__ w3p) {
  int idx = blockIdx.x * 256 + threadIdx.x;        // < 5120
  if (idx >= 80 * 64) return;
  int row = idx >> 6, c = idx & 63;
  float v = 0.f;
  if (row < 64) v = ctw[row * 64 + c];
  else if (row < 68) v = fcw[(row - 64) * 64 + c];
  w3p[idx] = f2bf(v);
}

// ---------------------------------------------------------------------------
// conv1 via MFMA. Staging: lane = pixel, channels in register-batched chunks
// of 16 (loads issued ahead of use -> 7 latency waits instead of 103).
// ---------------------------------------------------------------------------
__global__ __launch_bounds__(256) void conv1_mfma(
    const float* __restrict__ x, const unsigned short* __restrict__ w1p,
    const float* __restrict__ cb, const float* __restrict__ bng,
    const float* __restrict__ bnb, const float* __restrict__ bnm,
    const float* __restrict__ bnv, unsigned short* __restrict__ x1g) {
  __shared__ __align__(16) unsigned short im[23448];  // 15*15*104 + 48 guard
  const int b_  = blockIdx.x;
  const int tid = threadIdx.x;
  const float* xin = x + (size_t)b_ * 23175;          // 103*225

  for (int i = tid; i < 225; i += 256) im[i * 104 + 103] = 0;
  for (int i = tid; i < 48; i += 256) im[23400 + i] = 0;

  // coalesced + latency-batched staging
  if (tid < 225) {
    const float* src = xin + tid;
    unsigned short* dst = im + tid * 104;
    int ic = 0;
    for (; ic + 16 <= 103; ic += 16) {      // 6 batches of 16
      float v[16];
#pragma unroll
      for (int u = 0; u < 16; ++u) v[u] = src[(size_t)(ic + u) * 225];
#pragma unroll
      for (int u = 0; u < 16; u += 4) {
        ushort4 q;
        q.x = f2bf(v[u]); q.y = f2bf(v[u + 1]);
        q.z = f2bf(v[u + 2]); q.w = f2bf(v[u + 3]);
        *(ushort4*)(dst + ic + u) = q;
      }
    }
    {  // tail: ic = 96..102 (7)
      float v[7];
#pragma unroll
      for (int u = 0; u < 7; ++u) v[u] = src[(size_t)(96 + u) * 225];
#pragma unroll
      for (int u = 0; u < 7; ++u) dst[96 + u] = f2bf(v[u]);
    }
  }
  __syncthreads();

  const int lane = tid & 63, wid = tid >> 6;
  const int ln = lane & 15, kg = lane >> 4;

  int rb[3], pv[3];
#pragma unroll
  for (int nt = 0; nt < 3; ++nt) {
    int pix = (wid * 3 + nt) * 16 + ln;
    pv[nt] = (pix < 169);
    if (pix >= 169) pix = 0;
    int oy = pix / 13, ox = pix - oy * 13;
    rb[nt] = (oy * 15 + ox) * 208 + kg * 16;
  }

  f32x4 acc[2][3];
#pragma unroll
  for (int mt = 0; mt < 2; ++mt)
#pragma unroll
    for (int nt = 0; nt < 3; ++nt) acc[mt][nt] = (f32x4){0.f, 0.f, 0.f, 0.f};

  const unsigned short* wbase = w1p + (size_t)ln * 128 + kg * 8;
  const char* imb = (const char*)im;

  for (int ky = 0; ky < 3; ++ky) {
    for (int kx = 0; kx < 3; ++kx) {
      const int tap = ky * 3 + kx;
      const int tsh = (ky * 15 + kx) * 208;
      const unsigned short* wp = wbase + tap * 4096;
      bf16x8 a0[4], a1[4];
#pragma unroll
      for (int kt = 0; kt < 4; ++kt) {
        a0[kt] = *(const bf16x8*)(wp + kt * 32);
        a1[kt] = *(const bf16x8*)(wp + 2048 + kt * 32);
      }
#pragma unroll
      for (int kt = 0; kt < 4; ++kt) {
#pragma unroll
        for (int nt = 0; nt < 3; ++nt) {
          bf16x8 bv = *(const bf16x8*)(imb + rb[nt] + tsh + kt * 64);
          acc[0][nt] = __builtin_amdgcn_mfma_f32_16x16x32_bf16(a0[kt], bv, acc[0][nt], 0, 0, 0);
          acc[1][nt] = __builtin_amdgcn_mfma_f32_16x16x32_bf16(a1[kt], bv, acc[1][nt], 0, 0, 0);
        }
      }
    }
  }

#pragma unroll
  for (int mt = 0; mt < 2; ++mt) {
#pragma unroll
    for (int nt = 0; nt < 3; ++nt) {
      if (!pv[nt]) continue;
      int pix = (wid * 3 + nt) * 16 + ln;
      unsigned short* dst = x1g + ((size_t)b_ * 169 + pix) * 32;
      f32x4 a = acc[mt][nt];
#pragma unroll
      for (int r = 0; r < 4; ++r) {
        int oc = mt * 16 + kg * 4 + r;
        float val = a[r] + cb[oc];
        val = LEAKY1(val);
        float sc = bng[oc] * rsqrtf(bnv[oc] + 1e-5f);
        float sh = bnb[oc] - bnm[oc] * sc;
        dst[oc] = f2bf(val * sc + sh);
      }
    }
  }
}

// ---------------------------------------------------------------------------
// Fused conv2 (MFMA) + SAM + SGraph + DGraph. One block per batch.
// conv2 epilogue writes x2 (fp32 output) AND flatT bf16 into LDS, so the
// SAM stage needs no global staging. LDS regions overlaid: 45.4 KB total.
// ---------------------------------------------------------------------------
__global__ __launch_bounds__(256) void conv2_sam(
    const unsigned short* __restrict__ x1g, const unsigned short* __restrict__ w2p,
    const float* __restrict__ cb, const float* __restrict__ bng,
    const float* __restrict__ bnb, const float* __restrict__ bnm,
    const float* __restrict__ bnv,
    const unsigned short* __restrict__ w3p, // [80][64] bf16 (ctw;fcw;0)
    const float* __restrict__ conv_t_b,
    const float* __restrict__ s_adj_w, const float* __restrict__ s_w_w,
    const float* __restrict__ s_w_b,
    const float* __restrict__ d_co_w, const float* __restrict__ d_co_b,
    const float* __restrict__ d_gamma,
    const float* __restrict__ d_dw_w, const float* __restrict__ d_dw_b,
    float* __restrict__ x2out, float* __restrict__ x6) {
  __shared__ __align__(16) char smem[45440];
  // region A [0, 17408): im2 [169][40] bf16 (13520 B), later s_xt [64][136] bf16
  unsigned short* im2    = (unsigned short*)smem;
  unsigned short* s_xt   = (unsigned short*)smem;
  // region B [17408, 35840): s_flatT [128][72] bf16 (18432 B), later s_att [64][66] f32
  unsigned short* s_flatT = (unsigned short*)(smem + 17408);
  float*          s_att   = (float*)(smem + 17408);
  // region D [35840, 40192): s_mask [16][136] bf16
  unsigned short* s_mask = (unsigned short*)(smem + 35840);
  // region E [40192, ...): small f32 arrays
  float* s_x3   = (float*)(smem + 40192);  // [64][4]
  float* s_a    = s_x3 + 256;
  float* s_x4   = s_a + 256;
  float* s_xg   = s_x4 + 256;
  float* s_y    = s_xg + 256;
  float* s_dadj = s_y + 256;               // [4][4]

  const int b_  = blockIdx.x;
  const int tid = threadIdx.x;

  // P0: zero pads; stage x1g -> im2
  for (int i = tid; i < 252; i += 256) ((int*)(s_flatT + 121 * 72))[i] = 0; // rows 121-127
  for (int i = tid; i < 1088; i += 256) ((int*)s_mask)[i] = 0;
  for (int i = tid; i < 676; i += 256) {
    int pix = i >> 2, icg = i & 3;
    const uint4* src = (const uint4*)(x1g + ((size_t)b_ * 169 + pix) * 32 + icg * 8);
    *(uint4*)(im2 + pix * 40 + icg * 8) = *src;
  }
  __syncthreads();

  const int lane = tid & 63, wid = tid >> 6;
  const int ln = lane & 15, kg = lane >> 4;

  // P1: conv2 MFMA
  int rb[2], pv[2];
#pragma unroll
  for (int nt = 0; nt < 2; ++nt) {
    int pix = (wid * 2 + nt) * 16 + ln;
    pv[nt] = (pix < 121);
    if (pix >= 121) pix = 0;
    int oy = pix / 11, ox = pix - oy * 11;
    rb[nt] = (oy * 13 + ox) * 80 + kg * 16;
  }

  f32x4 acc2[4][2];
#pragma unroll
  for (int mt = 0; mt < 4; ++mt)
#pragma unroll
    for (int nt = 0; nt < 2; ++nt) acc2[mt][nt] = (f32x4){0.f, 0.f, 0.f, 0.f};

  {
    const unsigned short* wbase = w2p + (size_t)ln * 32 + kg * 8;
    const char* imb = (const char*)im2;
    for (int ky = 0; ky < 3; ++ky) {
      for (int kx = 0; kx < 3; ++kx) {
        const int tap = ky * 3 + kx;
        const int tsh = (ky * 13 + kx) * 80;
        const unsigned short* wp = wbase + tap * 2048;
        bf16x8 a[4];
#pragma unroll
        for (int mt = 0; mt < 4; ++mt) a[mt] = *(const bf16x8*)(wp + mt * 512);
#pragma unroll
        for (int nt = 0; nt < 2; ++nt) {
          bf16x8 bv = *(const bf16x8*)(imb + rb[nt] + tsh);
#pragma unroll
          for (int mt = 0; mt < 4; ++mt)
            acc2[mt][nt] = __builtin_amdgcn_mfma_f32_16x16x32_bf16(a[mt], bv, acc2[mt][nt], 0, 0, 0);
        }
      }
    }
  }

  // epilogue: x2 (fp32, global) + flatT (bf16, LDS [pix][oc])
#pragma unroll
  for (int mt = 0; mt < 4; ++mt) {
#pragma unroll
    for (int nt = 0; nt < 2; ++nt) {
      if (!pv[nt]) continue;
      int pix = (wid * 2 + nt) * 16 + ln;
      f32x4 a = acc2[mt][nt];
      ushort4 q;
      float vv[4];
#pragma unroll
      for (int r = 0; r < 4; ++r) {
        int oc = mt * 16 + kg * 4 + r;
        float val = a[r] + cb[oc];
        val = LEAKY1(val);
        float sc = bng[oc] * rsqrtf(bnv[oc] + 1e-5f);
        float sh = bnb[oc] - bnm[oc] * sc;
        vv[r] = val * sc + sh;
        x2out[((size_t)b_ * 64 + oc) * 121 + pix] = vv[r];
      }
      q.x = f2bf(vv[0]); q.y = f2bf(vv[1]); q.z = f2bf(vv[2]); q.w = f2bf(vv[3]);
      *(ushort4*)(s_flatT + pix * 72 + mt * 16 + kg * 4) = q;
    }
  }
  __syncthreads();

  // P2: GEMM1  D[80][128] = W3[80x64] * flatT'[64x128]
  for (int t = wid * 10; t < wid * 10 + 10; ++t) {
    const int mt = t >> 3, nt = t & 7;
    f32x4 acc = (f32x4){0.f, 0.f, 0.f, 0.f};
#pragma unroll
    for (int k0 = 0; k0 < 64; k0 += 32) {
      bf16x8 af = *(const bf16x8*)(w3p + (mt * 16 + ln) * 64 + k0 + kg * 8);
      bf16x8 bf_ = *(const bf16x8*)(s_flatT + (nt * 16 + ln) * 72 + k0 + kg * 8);
      acc = __builtin_amdgcn_mfma_f32_16x16x32_bf16(af, bf_, acc, 0, 0, 0);
    }
    const int l = nt * 16 + ln;
#pragma unroll
    for (int r = 0; r < 4; ++r) {
      int row = mt * 16 + kg * 4 + r;
      if (row < 64) s_xt[row * 136 + l] = f2bf(acc[r] + conv_t_b[row]);
      else if (row < 68) s_mask[(row - 64) * 136 + l] = f2bf(1.f / (1.f + __expf(-acc[r])));
    }
  }
  __syncthreads();
  if (tid < 28) s_mask[(tid / 7) * 136 + 121 + tid % 7] = 0;  // re-zero pad cols
  __syncthreads();

  // P3: GEMM2  x3[64][4] = xt[64x128] * mask^T[128x16]
  {
    f32x4 acc = (f32x4){0.f, 0.f, 0.f, 0.f};
#pragma unroll
    for (int k0 = 0; k0 < 128; k0 += 32) {
      bf16x8 af = *(const bf16x8*)(s_xt + (wid * 16 + ln) * 136 + k0 + kg * 8);
      bf16x8 bf_ = *(const bf16x8*)(s_mask + ln * 136 + k0 + kg * 8);
      acc = __builtin_amdgcn_mfma_f32_16x16x32_bf16(af, bf_, acc, 0, 0, 0);
    }
    if (ln < 4) {
#pragma unroll
      for (int r = 0; r < 4; ++r) s_x3[(wid * 16 + kg * 4 + r) * 4 + ln] = acc[r];
    }
  }
  __syncthreads();

  // a[f][m] = leaky(sum_n s_adj_w[m][n]*x3[f][n], 0.2)
  {
    int fi = tid >> 2, m = tid & 3;
    float s = 0.f;
#pragma unroll
    for (int n = 0; n < 4; ++n) s = fmaf(s_adj_w[m * 4 + n], s_x3[fi * 4 + n], s);
    s_a[fi * 4 + m] = LEAKY2(s);
  }
  __syncthreads();

  // x4 = leaky(s_w_w*a + b) + x3
  {
    int o = tid >> 2, n = tid & 3;
    float s = s_w_b[o];
    for (int ff = 0; ff < 64; ++ff) s = fmaf(s_w_w[o * 64 + ff], s_a[ff * 4 + n], s);
    s = LEAKY2(s);
    s_x4[o * 4 + n] = s + s_x3[o * 4 + n];
  }
  __syncthreads();

  // energy[c][d]
  for (int i = tid; i < 4096; i += 256) {
    int c = i >> 6, d = i & 63;
    float s = 0.f;
#pragma unroll
    for (int n = 0; n < 4; ++n) s = fmaf(s_x4[c * 4 + n], s_x4[d * 4 + n], s);
    s_att[c * 66 + d] = s;
  }
  __syncthreads();

  // softmax of (rowmax - energy) == exp(rowmin - energy)/sum
  if (tid < 64) {
    float* row = s_att + tid * 66;
    float mn = 1e30f;
    for (int d = 0; d < 64; ++d) mn = fminf(mn, row[d]);
    float ssum = 0.f;
    for (int d = 0; d < 64; ++d) {
      float e = __expf(mn - row[d]);
      row[d] = e;
      ssum += e;
    }
    float inv = 1.f / ssum;
    for (int d = 0; d < 64; ++d) row[d] *= inv;
  }
  __syncthreads();

  const float gamma = d_gamma[0];
  {
    int c = tid >> 2, n = tid & 3;
    float s = 0.f;
    for (int d = 0; d < 64; ++d) s = fmaf(s_att[c * 66 + d], s_x4[d * 4 + n], s);
    s_xg[c * 4 + n] = gamma * s + s_x4[c * 4 + n];
  }
  __syncthreads();

  if (tid < 16) {
    int m = tid >> 2, n = tid & 3;
    float s = d_co_b[m];
    for (int k = 0; k < 64; ++k) s = fmaf(d_co_w[m * 128 + k],      s_xg[k * 4 + n], s);
    for (int k = 0; k < 64; ++k) s = fmaf(d_co_w[m * 128 + 64 + k], s_x4[k * 4 + n], s);
    s_dadj[m * 4 + n] = 1.f / (1.f + __expf(-s));
  }
  __syncthreads();

  {
    int c = tid >> 2, m = tid & 3;
    float s = 0.f;
#pragma unroll
    for (int n = 0; n < 4; ++n) s = fmaf(s_x4[c * 4 + n], s_dadj[n * 4 + m], s);
    s_y[c * 4 + m] = LEAKY2(s);
  }
  __syncthreads();

  {
    int o = tid >> 2, n = tid & 3;
    float s = d_dw_b[o];
    for (int ff = 0; ff < 64; ++ff) s = fmaf(d_dw_w[o * 64 + ff], s_y[ff * 4 + n], s);
    s = LEAKY2(s);
    x6[(size_t)b_ * 256 + tid] = s + s_x4[tid];
  }
}

// ---------------------------------------------------------------------------
extern "C" void kernel_launch(void* const* d_in, const int* in_sizes, int n_in,
                              void* d_out, int out_size, void* d_ws, size_t ws_size,
                              hipStream_t stream) {
  const float* x     = (const float*)d_in[0];
  const float* c1w   = (const float*)d_in[1];
  const float* c1b   = (const float*)d_in[2];
  const float* bn1g  = (const float*)d_in[3];
  const float* bn1b  = (const float*)d_in[4];
  const float* bn1m  = (const float*)d_in[5];
  const float* bn1v  = (const float*)d_in[6];
  const float* c2w   = (const float*)d_in[7];
  const float* c2b   = (const float*)d_in[8];
  const float* bn2g  = (const float*)d_in[9];
  const float* bn2b  = (const float*)d_in[10];
  const float* bn2m  = (const float*)d_in[11];
  const float* bn2v  = (const float*)d_in[12];
  const float* fcw   = (const float*)d_in[13];
  const float* ctw   = (const float*)d_in[14];
  const float* ctb   = (const float*)d_in[15];
  const float* sadj  = (const float*)d_in[16];
  const float* sww   = (const float*)d_in[17];
  const float* swb   = (const float*)d_in[18];
  const float* dcow  = (const float*)d_in[19];
  const float* dcob  = (const float*)d_in[20];
  const float* dgam  = (const float*)d_in[21];
  const float* ddww  = (const float*)d_in[22];
  const float* ddwb  = (const float*)d_in[23];

  float* out = (float*)d_out;
  float* x6  = out;                      // [1024,256]
  float* x2  = out + (size_t)1024 * 256; // [1024,64,121]

  unsigned short* x1g = (unsigned short*)d_ws;         // [1024][169][32] bf16
  unsigned short* w1p = x1g + (size_t)1024 * 169 * 32; // [9][32][128]
  unsigned short* w2p = w1p + 9 * 32 * 128;            // [9][64][32]
  unsigned short* w3p = w2p + 9 * 64 * 32;             // [80][64]

  w1prep_kernel<<<144, 256, 0, stream>>>(c1w, w1p);
  w2prep_kernel<<<72, 256, 0, stream>>>(c2w, w2p);
  w3prep_kernel<<<20, 256, 0, stream>>>(ctw, fcw, w3p);
  conv1_mfma<<<1024, 256, 0, stream>>>(x, w1p, c1b, bn1g, bn1b, bn1m, bn1v, x1g);
  conv2_sam<<<1024, 256, 0, stream>>>(x1g, w2p, c2b, bn2g, bn2b, bn2m, bn2v,
                                      w3p, ctb, sadj, sww, swb, dcow, dcob, dgam,
                                      ddww, ddwb, x2, x6);
}